// Round 4
// baseline (414.988 us; speedup 1.0000x reference)
//
#include <hip/hip_runtime.h>

#define HIDDEN 32
#define FF 40
#define SEQ_T 512
#define RD 8     // ring depth; producer/consumer slot distance (disjoint mod 8)

typedef __attribute__((ext_vector_type(8))) short short8;
typedef __attribute__((ext_vector_type(4))) float float4v;
typedef __attribute__((ext_vector_type(4))) unsigned uint4v;
typedef __attribute__((ext_vector_type(2))) unsigned uint2v;

// ---------------------------------------------------------------------------
// R13 = R12 (4-wave occupancy split of R11's K=128 packed 3-term scheme) with
// the uninitialized-LDS hazard closed: ring k-slots 126/127 are READ by the
// B-frag loads but never written by store_s; if inherited LDS garbage there
// is a bf16 NaN/Inf pattern, MFMA computes 0*NaN = NaN (A' is 0 in those
// slots) and the recurrence explodes -- R12's NaN failure. The ring is now
// zeroed at block start (barrier before the prologue writes slot 0).
// wave0 = hh producer (3 steps/phase); waves 1-3 = ho consumers (1 step each:
// t = 3p-2+(wv-1)). 4 waves/SIMD fill the producer's latency gaps.
// ---------------------------------------------------------------------------

__global__ __launch_bounds__(256, 1) void rnn_prep(
    const float* __restrict__ W1hh, const float* __restrict__ b1hh,
    const float* __restrict__ W2hh, const float* __restrict__ b2hh,
    const float* __restrict__ W1ho, const float* __restrict__ b1ho,
    unsigned short* __restrict__ acatP)
{
    const int idx = blockIdx.x * 256 + threadIdx.x;
    if (idx >= 96 * 128) return;
    const int mrow = idx >> 7, s = idx & 127;

    // slot -> (contraction col, plane): plane 0 = hi(trunc), 1 = lo(RNE)
    int kcol, plane;
    if (s < 40)       { kcol = s;            plane = 0; }
    else if (s < 80)  { kcol = s - 40;       plane = 0; }  // Ah x S_lo
    else if (s < 120) { kcol = s - 80;       plane = 1; }  // Al x S_hi-dup
    else if (s < 124) { kcol = 40 + (s & 1); plane = 0; }  // Ah_u, Ah_b
    else if (s < 126) { kcol = 40 + (s & 1); plane = 1; }  // Al_u, Al_b
    else { acatP[idx] = 0; return; }

    const bool hh = mrow < 48;
    const int col = hh ? mrow : mrow - 48;
    float val = 0.f;
    if (col < FF) {
        const float* W1 = hh ? W1hh : W1ho;
        const float* b1 = hh ? b1hh : b1ho;
        if (kcol < FF) {
            for (int i = 0; i < HIDDEN; ++i)
                val = __builtin_fmaf(W2hh[kcol * HIDDEN + i], W1[i * FF + col], val);
        } else if (kcol == 40) {
            val = W1[HIDDEN * FF + col];
        } else {  // kcol == 41: folded bias channel
            val = b1[col];
            for (int i = 0; i < HIDDEN; ++i)
                val = __builtin_fmaf(b2hh[i], W1[i * FF + col], val);
        }
    }
    const unsigned vb = __builtin_bit_cast(unsigned, val);
    const unsigned short hi = (unsigned short)(vb >> 16);
    unsigned short out;
    if (plane == 0) {
        out = hi;
    } else {
        const float hif = __builtin_bit_cast(float, (unsigned)hi << 16);
        const float lo = val - hif;
        const unsigned lb = __builtin_bit_cast(unsigned, lo);
        out = (unsigned short)((lb + 0x7FFFu + ((lb >> 16) & 1u)) >> 16);
    }
    acatP[idx] = out;
}

__device__ __forceinline__ float sigmoid_fast(float x) {
    const float e = __builtin_amdgcn_exp2f(-x * 1.44269504088896341f);
    return __builtin_amdgcn_rcpf(1.0f + e);
}

// dword [hi16(v) : round-bf16(v - hi)] packer (u-channel)
__device__ __forceinline__ unsigned splitpack(float v) {
    const unsigned b = __builtin_bit_cast(unsigned, v);
    const unsigned hif = b & 0xFFFF0000u;
    const float rr = v - __builtin_bit_cast(float, hif);
    unsigned rb = __builtin_bit_cast(unsigned, rr) + 0x8000u;
    return __builtin_amdgcn_perm(b, rb, 0x07060302u);
}

// packs [bf16(hi) : bf16(lo)] with RNE; first operand lands in the LOW ushort
__device__ __forceinline__ unsigned cvt_pk_bf16(float lo, float hi) {
    unsigned r;
    asm("v_cvt_pk_bf16_f32 %0, %1, %2" : "=v"(r) : "v"(lo), "v"(hi));
    return r;
}

__global__ __launch_bounds__(256, 4) void rnn_main(
    const float* __restrict__ inputs,
    const unsigned short* __restrict__ acatP,
    const float* __restrict__ W1hh, const float* __restrict__ b1hh,
    const float* __restrict__ W1ho, const float* __restrict__ b1ho,
    const float* __restrict__ W2ho, const float* __restrict__ b2ho,
    float* __restrict__ ys)
{
    // 136-ushort rows (272 B): 16B-aligned for b128 reads; slots 128..135 pad
    __shared__ __align__(16) unsigned short ring[RD][16][136];   // 34816 B

    const int tid = threadIdx.x;
    const int wv  = __builtin_amdgcn_readfirstlane(tid >> 6);  // 0=hh prod, 1..3=ho cons
    const int l = tid & 63;
    const int r = l & 15;        // batch row within tile
    const int g = l >> 4;        // quad
    const size_t rowbase = (size_t)(blockIdx.x * 16 + r) * SEQ_T;
    const float* __restrict__ in_row = inputs + rowbase;

    // ---- zero the ring (kills the uninit-LDS NaN hazard at slots 126/127) ----
    {
        uint4v* zp = (uint4v*)&ring[0][0][0];
        const uint4v z4 = {0u, 0u, 0u, 0u};
#pragma unroll
        for (int i = 0; i < 9; ++i) {
            const int idx = tid + 256 * i;
            if (idx < 2176) zp[idx] = z4;    // 2176 * 16 B = 34816 B
        }
    }

    // ---- A-frags: producer hh m-tiles 0-2, consumers ho m-tiles 3-5 ----
    short8 A[3][4];
    const int mb = (wv == 0) ? 0 : 3;
#pragma unroll
    for (int mt = 0; mt < 3; ++mt)
#pragma unroll
        for (int ks = 0; ks < 4; ++ks)
            A[mt][ks] = *(const short8*)(acatP + ((mb + mt) * 16 + r) * 128 + ks * 32 + g * 8);

    float w2o_l[3][4];
#pragma unroll
    for (int mt = 0; mt < 3; ++mt)
#pragma unroll
        for (int q = 0; q < 4; ++q) {
            const int j = 16 * mt + 4 * g + q;
            w2o_l[mt][q] = (j < FF) ? W2ho[j] : 0.f;
        }
    const float b2o = b2ho[0];
    const bool out16 = (l < 16);

    auto load_frags = [&](int sl, short8 (&f)[4]) {
        const unsigned short* p = &ring[sl][r][0];
#pragma unroll
        for (int ks = 0; ks < 4; ++ks)
            f[ks] = *(const short8*)(p + ks * 32 + g * 8);
    };

    auto do_mfma = [&](const short8 (&f)[4], float4v (&acc)[3]) {
#pragma unroll
        for (int mt = 0; mt < 3; ++mt) acc[mt] = (float4v)0.f;
#pragma unroll
        for (int mt = 0; mt < 3; ++mt)
#pragma unroll
            for (int ks = 0; ks < 4; ++ks)
                acc[mt] = __builtin_amdgcn_mfma_f32_16x16x32_bf16(A[mt][ks], f[ks], acc[mt], 0, 0, 0);
    };

    // sigmoid + split-pack + ring store: hi@dword 2j, lo@20+2j, hi-dup@40+2j,
    // u/bias dwords @ 60..62 (g==3 quad)
    auto store_s = [&](int slot, const float4v (&z)[3], unsigned upk) {
        unsigned* bp = (unsigned*)&ring[slot][r][0];
#pragma unroll
        for (int mt = 0; mt < 3; ++mt) {
            const float s0 = sigmoid_fast(z[mt][0]);
            const float s1 = sigmoid_fast(z[mt][1]);
            const float s2 = sigmoid_fast(z[mt][2]);
            const float s3 = sigmoid_fast(z[mt][3]);
            const unsigned h01 = cvt_pk_bf16(s0, s1);
            const unsigned h23 = cvt_pk_bf16(s2, s3);
            const float r0 = s0 - __builtin_bit_cast(float, h01 << 16);
            const float r1 = s1 - __builtin_bit_cast(float, h01 & 0xFFFF0000u);
            const float r2 = s2 - __builtin_bit_cast(float, h23 << 16);
            const float r3 = s3 - __builtin_bit_cast(float, h23 & 0xFFFF0000u);
            const unsigned l01 = cvt_pk_bf16(r0, r1);
            const unsigned l23 = cvt_pk_bf16(r2, r3);
            const int j = 4 * mt + g;
            if (j < 10) {
                uint2v hp, lp;
                hp.x = h01; hp.y = h23;
                lp.x = l01; lp.y = l23;
                *(uint2v*)(bp + 2 * j) = hp;        // S_hi
                *(uint2v*)(bp + 20 + 2 * j) = lp;   // S_lo
                *(uint2v*)(bp + 40 + 2 * j) = hp;   // S_hi dup
            }
        }
        if (g == 3) {
            uint2v up;
            up.x = (upk >> 16) | 0x3F800000u;   // [u_hi : bf16(1.0)]
            up.y = upk & 0xFFFFu;               // [u_lo : 0]
            *(uint2v*)(bp + 60) = up;           // slots 120..123
            bp[62] = up.x;                      // slots 124,125 (dup for Al)
        }
    };

    __syncthreads();   // zeroing complete before prologue writes slot 0

    // ---- prologue: t = 0 ----
    float uc[3];
    if (wv == 0) {
        const float u0 = in_row[0];
        float4v z[3];
#pragma unroll
        for (int mt = 0; mt < 3; ++mt)
#pragma unroll
            for (int q = 0; q < 4; ++q) {
                const int n = 16 * mt + 4 * g + q;
                const int nc = n < FF ? n : FF - 1;
                z[mt][q] = __builtin_fmaf(u0, W1hh[HIDDEN * FF + nc], b1hh[nc]);
            }
        store_s(0, z, splitpack(in_row[1]));   // slot 0 = S(0) + u(1)
        uc[0] = in_row[2]; uc[1] = in_row[3]; uc[2] = in_row[4];
    } else if (wv == 1) {
        const float u0 = in_row[0];
        float op = 0.f;
#pragma unroll
        for (int mt = 0; mt < 3; ++mt)
#pragma unroll
            for (int q = 0; q < 4; ++q) {
                const int n = 16 * mt + 4 * g + q;
                const int nc = n < FF ? n : FF - 1;
                const float so = sigmoid_fast(
                    __builtin_fmaf(u0, W1ho[HIDDEN * FF + nc], b1ho[nc]));
                op = __builtin_fmaf(so, w2o_l[mt][q], op);
            }
        op += __shfl_xor(op, 16);
        op += __shfl_xor(op, 32);
        if (out16) ys[rowbase] = op + b2o;
    }
    __syncthreads();

    // ---- phase loop: wave0 runs steps [3p+1..3p+3]; wave w (1..3) runs the
    // single step t = 3p-2+(w-1)  (covers every t in 1..511 exactly once) ----
    for (int p = 0; p < 172; ++p) {
        if (wv == 0) {
            const int tb = 3 * p + 1;
            float un[3];
#pragma unroll
            for (int i = 0; i < 3; ++i) {
                int tn = tb + 4 + i; tn = tn < SEQ_T ? tn : SEQ_T - 1;
                un[i] = in_row[tn];     // u for next phase
            }
#pragma unroll
            for (int i = 0; i < 3; ++i) {
                const int t = tb + i;
                if (t < SEQ_T) {
                    short8 f[4];
                    load_frags((t - 1) & (RD - 1), f);
                    float4v z[3];
                    do_mfma(f, z);
                    store_s(t & (RD - 1), z, splitpack(uc[i]));
                }
            }
            uc[0] = un[0]; uc[1] = un[1]; uc[2] = un[2];
        } else {
            const int t = 3 * p - 2 + (wv - 1);
            if (t >= 1 && t < SEQ_T) {
                short8 f[4];
                load_frags((t - 1) & (RD - 1), f);
                float4v acc[3];
                do_mfma(f, acc);
                float op = 0.f;
#pragma unroll
                for (int mt = 0; mt < 3; ++mt)
#pragma unroll
                    for (int q = 0; q < 4; ++q)
                        op = __builtin_fmaf(sigmoid_fast(acc[mt][q]),
                                            w2o_l[mt][q], op);
                op += __shfl_xor(op, 16);
                op += __shfl_xor(op, 32);
                if (out16) ys[rowbase + t] = op + b2o;
            }
        }
        __syncthreads();
    }
}

extern "C" void kernel_launch(void* const* d_in, const int* in_sizes, int n_in,
                              void* d_out, int out_size, void* d_ws, size_t ws_size,
                              hipStream_t stream) {
    const float* inputs = (const float*)d_in[0];
    const float* W1hh   = (const float*)d_in[1];
    const float* b1hh   = (const float*)d_in[2];
    const float* W2hh   = (const float*)d_in[3];
    const float* b2hh   = (const float*)d_in[4];
    const float* W1ho   = (const float*)d_in[5];
    const float* b1ho   = (const float*)d_in[6];
    const float* W2ho   = (const float*)d_in[7];
    const float* b2ho   = (const float*)d_in[8];
    float* ys = (float*)d_out;

    unsigned short* acatP = (unsigned short*)d_ws;    // 96*128 ushorts

    const int B = in_sizes[0] / SEQ_T;   // 16384

    rnn_prep<<<(96 * 128 + 255) / 256, 256, 0, stream>>>(
        W1hh, b1hh, W2hh, b2hh, W1ho, b1ho, acatP);

    const int blocks = B / 16;           // 1024 blocks x 4 waves (1 hh + 3 ho)
    rnn_main<<<blocks, 256, 0, stream>>>(
        inputs, acatP, W1hh, b1hh, W1ho, b1ho, W2ho, b2ho, ys);
}

// Round 5
// 379.117 us; speedup vs baseline: 1.0946x; 1.0946x over previous
//
#include <hip/hip_runtime.h>

#define HIDDEN 32
#define FF 40
#define SEQ_T 512
#define RD 8     // ring depth; producer/consumer slot distance (disjoint mod 8)

typedef __attribute__((ext_vector_type(8))) short short8;
typedef __attribute__((ext_vector_type(4))) float float4v;
typedef __attribute__((ext_vector_type(4))) unsigned uint4v;
typedef __attribute__((ext_vector_type(2))) unsigned uint2v;

// ---------------------------------------------------------------------------
// R14 = R13 (4-wave split, K=128 packed 3-term MFMA, zeroed ring) + producer
// critical-path surgery:
//  (1) wave0 (the serial hh producer) runs at s_setprio(1) for the whole
//      kernel. R13 showed the phase period is pinned by the producer's serial
//      recurrence (720 ns/step, ~3x its dependency-chain latency) while
//      consumer waves steal issue slots. Priority makes the producer's chain
//      tight; consumers (prio 0) fill its true stall cycles. (T5 role-split.)
//  (2) MFMA accumulation split 4-deep -> two independent 2-deep chains + one
//      vector add per m-tile: removes 2 dependent MFMA latencies per step
//      from the serial chain. fp32 re-association only (output floor is the
//      bf16 ulp).
// ---------------------------------------------------------------------------

__global__ __launch_bounds__(256, 1) void rnn_prep(
    const float* __restrict__ W1hh, const float* __restrict__ b1hh,
    const float* __restrict__ W2hh, const float* __restrict__ b2hh,
    const float* __restrict__ W1ho, const float* __restrict__ b1ho,
    unsigned short* __restrict__ acatP)
{
    const int idx = blockIdx.x * 256 + threadIdx.x;
    if (idx >= 96 * 128) return;
    const int mrow = idx >> 7, s = idx & 127;

    // slot -> (contraction col, plane): plane 0 = hi(trunc), 1 = lo(RNE)
    int kcol, plane;
    if (s < 40)       { kcol = s;            plane = 0; }
    else if (s < 80)  { kcol = s - 40;       plane = 0; }  // Ah x S_lo
    else if (s < 120) { kcol = s - 80;       plane = 1; }  // Al x S_hi-dup
    else if (s < 124) { kcol = 40 + (s & 1); plane = 0; }  // Ah_u, Ah_b
    else if (s < 126) { kcol = 40 + (s & 1); plane = 1; }  // Al_u, Al_b
    else { acatP[idx] = 0; return; }

    const bool hh = mrow < 48;
    const int col = hh ? mrow : mrow - 48;
    float val = 0.f;
    if (col < FF) {
        const float* W1 = hh ? W1hh : W1ho;
        const float* b1 = hh ? b1hh : b1ho;
        if (kcol < FF) {
            for (int i = 0; i < HIDDEN; ++i)
                val = __builtin_fmaf(W2hh[kcol * HIDDEN + i], W1[i * FF + col], val);
        } else if (kcol == 40) {
            val = W1[HIDDEN * FF + col];
        } else {  // kcol == 41: folded bias channel
            val = b1[col];
            for (int i = 0; i < HIDDEN; ++i)
                val = __builtin_fmaf(b2hh[i], W1[i * FF + col], val);
        }
    }
    const unsigned vb = __builtin_bit_cast(unsigned, val);
    const unsigned short hi = (unsigned short)(vb >> 16);
    unsigned short out;
    if (plane == 0) {
        out = hi;
    } else {
        const float hif = __builtin_bit_cast(float, (unsigned)hi << 16);
        const float lo = val - hif;
        const unsigned lb = __builtin_bit_cast(unsigned, lo);
        out = (unsigned short)((lb + 0x7FFFu + ((lb >> 16) & 1u)) >> 16);
    }
    acatP[idx] = out;
}

__device__ __forceinline__ float sigmoid_fast(float x) {
    const float e = __builtin_amdgcn_exp2f(-x * 1.44269504088896341f);
    return __builtin_amdgcn_rcpf(1.0f + e);
}

// dword [hi16(v) : round-bf16(v - hi)] packer (u-channel)
__device__ __forceinline__ unsigned splitpack(float v) {
    const unsigned b = __builtin_bit_cast(unsigned, v);
    const unsigned hif = b & 0xFFFF0000u;
    const float rr = v - __builtin_bit_cast(float, hif);
    unsigned rb = __builtin_bit_cast(unsigned, rr) + 0x8000u;
    return __builtin_amdgcn_perm(b, rb, 0x07060302u);
}

// packs [bf16(hi) : bf16(lo)] with RNE; first operand lands in the LOW ushort
__device__ __forceinline__ unsigned cvt_pk_bf16(float lo, float hi) {
    unsigned r;
    asm("v_cvt_pk_bf16_f32 %0, %1, %2" : "=v"(r) : "v"(lo), "v"(hi));
    return r;
}

__global__ __launch_bounds__(256, 4) void rnn_main(
    const float* __restrict__ inputs,
    const unsigned short* __restrict__ acatP,
    const float* __restrict__ W1hh, const float* __restrict__ b1hh,
    const float* __restrict__ W1ho, const float* __restrict__ b1ho,
    const float* __restrict__ W2ho, const float* __restrict__ b2ho,
    float* __restrict__ ys)
{
    // 136-ushort rows (272 B): 16B-aligned for b128 reads; slots 128..135 pad
    __shared__ __align__(16) unsigned short ring[RD][16][136];   // 34816 B

    const int tid = threadIdx.x;
    const int wv  = __builtin_amdgcn_readfirstlane(tid >> 6);  // 0=hh prod, 1..3=ho cons
    const int l = tid & 63;
    const int r = l & 15;        // batch row within tile
    const int g = l >> 4;        // quad
    const size_t rowbase = (size_t)(blockIdx.x * 16 + r) * SEQ_T;
    const float* __restrict__ in_row = inputs + rowbase;

    // producer wave gets issue priority: its serial recurrence IS the clock;
    // consumer waves (prio 0) fill its stall cycles only
    if (wv == 0) __builtin_amdgcn_s_setprio(1);

    // ---- zero the ring (kills the uninit-LDS NaN hazard at slots 126/127) ----
    {
        uint4v* zp = (uint4v*)&ring[0][0][0];
        const uint4v z4 = {0u, 0u, 0u, 0u};
#pragma unroll
        for (int i = 0; i < 9; ++i) {
            const int idx = tid + 256 * i;
            if (idx < 2176) zp[idx] = z4;    // 2176 * 16 B = 34816 B
        }
    }

    // ---- A-frags: producer hh m-tiles 0-2, consumers ho m-tiles 3-5 ----
    short8 A[3][4];
    const int mb = (wv == 0) ? 0 : 3;
#pragma unroll
    for (int mt = 0; mt < 3; ++mt)
#pragma unroll
        for (int ks = 0; ks < 4; ++ks)
            A[mt][ks] = *(const short8*)(acatP + ((mb + mt) * 16 + r) * 128 + ks * 32 + g * 8);

    float w2o_l[3][4];
#pragma unroll
    for (int mt = 0; mt < 3; ++mt)
#pragma unroll
        for (int q = 0; q < 4; ++q) {
            const int j = 16 * mt + 4 * g + q;
            w2o_l[mt][q] = (j < FF) ? W2ho[j] : 0.f;
        }
    const float b2o = b2ho[0];
    const bool out16 = (l < 16);

    auto load_frags = [&](int sl, short8 (&f)[4]) {
        const unsigned short* p = &ring[sl][r][0];
#pragma unroll
        for (int ks = 0; ks < 4; ++ks)
            f[ks] = *(const short8*)(p + ks * 32 + g * 8);
    };

    // two independent 2-deep MFMA chains per m-tile + one vector add:
    // shortens the serial dependent-MFMA latency (4L -> 2L + add)
    auto do_mfma = [&](const short8 (&f)[4], float4v (&acc)[3]) {
#pragma unroll
        for (int mt = 0; mt < 3; ++mt) {
            float4v a = (float4v)0.f, b = (float4v)0.f;
            a = __builtin_amdgcn_mfma_f32_16x16x32_bf16(A[mt][0], f[0], a, 0, 0, 0);
            b = __builtin_amdgcn_mfma_f32_16x16x32_bf16(A[mt][2], f[2], b, 0, 0, 0);
            a = __builtin_amdgcn_mfma_f32_16x16x32_bf16(A[mt][1], f[1], a, 0, 0, 0);
            b = __builtin_amdgcn_mfma_f32_16x16x32_bf16(A[mt][3], f[3], b, 0, 0, 0);
            acc[mt] = a + b;
        }
    };

    // sigmoid + split-pack + ring store: hi@dword 2j, lo@20+2j, hi-dup@40+2j,
    // u/bias dwords @ 60..62 (g==3 quad)
    auto store_s = [&](int slot, const float4v (&z)[3], unsigned upk) {
        unsigned* bp = (unsigned*)&ring[slot][r][0];
#pragma unroll
        for (int mt = 0; mt < 3; ++mt) {
            const float s0 = sigmoid_fast(z[mt][0]);
            const float s1 = sigmoid_fast(z[mt][1]);
            const float s2 = sigmoid_fast(z[mt][2]);
            const float s3 = sigmoid_fast(z[mt][3]);
            const unsigned h01 = cvt_pk_bf16(s0, s1);
            const unsigned h23 = cvt_pk_bf16(s2, s3);
            const float r0 = s0 - __builtin_bit_cast(float, h01 << 16);
            const float r1 = s1 - __builtin_bit_cast(float, h01 & 0xFFFF0000u);
            const float r2 = s2 - __builtin_bit_cast(float, h23 << 16);
            const float r3 = s3 - __builtin_bit_cast(float, h23 & 0xFFFF0000u);
            const unsigned l01 = cvt_pk_bf16(r0, r1);
            const unsigned l23 = cvt_pk_bf16(r2, r3);
            const int j = 4 * mt + g;
            if (j < 10) {
                uint2v hp, lp;
                hp.x = h01; hp.y = h23;
                lp.x = l01; lp.y = l23;
                *(uint2v*)(bp + 2 * j) = hp;        // S_hi
                *(uint2v*)(bp + 20 + 2 * j) = lp;   // S_lo
                *(uint2v*)(bp + 40 + 2 * j) = hp;   // S_hi dup
            }
        }
        if (g == 3) {
            uint2v up;
            up.x = (upk >> 16) | 0x3F800000u;   // [u_hi : bf16(1.0)]
            up.y = upk & 0xFFFFu;               // [u_lo : 0]
            *(uint2v*)(bp + 60) = up;           // slots 120..123
            bp[62] = up.x;                      // slots 124,125 (dup for Al)
        }
    };

    __syncthreads();   // zeroing complete before prologue writes slot 0

    // ---- prologue: t = 0 ----
    float uc[3];
    if (wv == 0) {
        const float u0 = in_row[0];
        float4v z[3];
#pragma unroll
        for (int mt = 0; mt < 3; ++mt)
#pragma unroll
            for (int q = 0; q < 4; ++q) {
                const int n = 16 * mt + 4 * g + q;
                const int nc = n < FF ? n : FF - 1;
                z[mt][q] = __builtin_fmaf(u0, W1hh[HIDDEN * FF + nc], b1hh[nc]);
            }
        store_s(0, z, splitpack(in_row[1]));   // slot 0 = S(0) + u(1)
        uc[0] = in_row[2]; uc[1] = in_row[3]; uc[2] = in_row[4];
    } else if (wv == 1) {
        const float u0 = in_row[0];
        float op = 0.f;
#pragma unroll
        for (int mt = 0; mt < 3; ++mt)
#pragma unroll
            for (int q = 0; q < 4; ++q) {
                const int n = 16 * mt + 4 * g + q;
                const int nc = n < FF ? n : FF - 1;
                const float so = sigmoid_fast(
                    __builtin_fmaf(u0, W1ho[HIDDEN * FF + nc], b1ho[nc]));
                op = __builtin_fmaf(so, w2o_l[mt][q], op);
            }
        op += __shfl_xor(op, 16);
        op += __shfl_xor(op, 32);
        if (out16) ys[rowbase] = op + b2o;
    }
    __syncthreads();

    // ---- phase loop: wave0 runs steps [3p+1..3p+3]; wave w (1..3) runs the
    // single step t = 3p-2+(w-1)  (covers every t in 1..511 exactly once) ----
    for (int p = 0; p < 172; ++p) {
        if (wv == 0) {
            const int tb = 3 * p + 1;
            float un[3];
#pragma unroll
            for (int i = 0; i < 3; ++i) {
                int tn = tb + 4 + i; tn = tn < SEQ_T ? tn : SEQ_T - 1;
                un[i] = in_row[tn];     // u for next phase
            }
#pragma unroll
            for (int i = 0; i < 3; ++i) {
                const int t = tb + i;
                if (t < SEQ_T) {
                    short8 f[4];
                    load_frags((t - 1) & (RD - 1), f);
                    float4v z[3];
                    do_mfma(f, z);
                    store_s(t & (RD - 1), z, splitpack(uc[i]));
                }
            }
            uc[0] = un[0]; uc[1] = un[1]; uc[2] = un[2];
        } else {
            const int t = 3 * p - 2 + (wv - 1);
            if (t >= 1 && t < SEQ_T) {
                short8 f[4];
                load_frags((t - 1) & (RD - 1), f);
                float4v acc[3];
                do_mfma(f, acc);
                float op = 0.f;
#pragma unroll
                for (int mt = 0; mt < 3; ++mt)
#pragma unroll
                    for (int q = 0; q < 4; ++q)
                        op = __builtin_fmaf(sigmoid_fast(acc[mt][q]),
                                            w2o_l[mt][q], op);
                op += __shfl_xor(op, 16);
                op += __shfl_xor(op, 32);
                if (out16) ys[rowbase + t] = op + b2o;
            }
        }
        __syncthreads();
    }
}

extern "C" void kernel_launch(void* const* d_in, const int* in_sizes, int n_in,
                              void* d_out, int out_size, void* d_ws, size_t ws_size,
                              hipStream_t stream) {
    const float* inputs = (const float*)d_in[0];
    const float* W1hh   = (const float*)d_in[1];
    const float* b1hh   = (const float*)d_in[2];
    const float* W2hh   = (const float*)d_in[3];
    const float* b2hh   = (const float*)d_in[4];
    const float* W1ho   = (const float*)d_in[5];
    const float* b1ho   = (const float*)d_in[6];
    const float* W2ho   = (const float*)d_in[7];
    const float* b2ho   = (const float*)d_in[8];
    float* ys = (float*)d_out;

    unsigned short* acatP = (unsigned short*)d_ws;    // 96*128 ushorts

    const int B = in_sizes[0] / SEQ_T;   // 16384

    rnn_prep<<<(96 * 128 + 255) / 256, 256, 0, stream>>>(
        W1hh, b1hh, W2hh, b2hh, W1ho, b1ho, acatP);

    const int blocks = B / 16;           // 1024 blocks x 4 waves (1 hh + 3 ho)
    rnn_main<<<blocks, 256, 0, stream>>>(
        inputs, acatP, W1hh, b1hh, W1ho, b1ho, W2ho, b2ho, ys);
}